// Round 1
// baseline (260.522 us; speedup 1.0000x reference)
//
#include <hip/hip_runtime.h>

// Problem constants
#define MROWS 512            // B*S
#define VDIM  50257          // vocab
#define KP    50272          // VDIM padded to multiple of 32 (= 32*1571)
#define NDIM  1024           // D
#define NSTEPS (KP / 32)     // 1571 K-steps of 32
#define KSPLIT 16
#define SC    99             // ceil(NSTEPS / KSPLIT)
#define PRED_OFF 524288      // 512*1024
#define PP_OFF   524800      // + 512

typedef unsigned short u16;
typedef unsigned int   u32;
typedef __bf16 bf16x8 __attribute__((ext_vector_type(8)));
typedef float  f32x4  __attribute__((ext_vector_type(4)));

__device__ __forceinline__ u16 f2bf(float f) {
  u32 u = __float_as_uint(f);
  u32 r = (u + 0x7fffu + ((u >> 16) & 1u)) >> 16;  // RNE
  return (u16)r;
}

__device__ __forceinline__ void gl_lds16(const u16* g, u16* l) {
  __builtin_amdgcn_global_load_lds(
      (const __attribute__((address_space(1))) u32*)(g),
      (__attribute__((address_space(3))) u32*)(l), 16, 0, 0);
}

// ---------------------------------------------------------------------------
// Kernel 1: per-row copy + argmax + bf16 convert of pred_probs; zero emb row.
// grid = 512 blocks (one per (b,s) row), 256 threads.
// ---------------------------------------------------------------------------
__global__ __launch_bounds__(256) void prep_kernel(const float* __restrict__ P,
                                                   float* __restrict__ out,
                                                   u16* __restrict__ A)
{
  const int m   = blockIdx.x;
  const int tid = threadIdx.x;
  const float* src = P + (size_t)m * VDIM;
  float*       cpy = out + PP_OFF + (size_t)m * VDIM;
  u16*        arow = A + (size_t)m * KP;

  // zero pred_emb row m (1024 floats, 16B-aligned)
  { f32x4 z = {}; *(f32x4*)(out + (size_t)m * NDIM + tid * 4) = z; }

  float bv = -3.4e38f;
  int   bi = 0;

  // flat float index of row base is m*VDIM; VDIM%4==1 -> head of h elems to
  // reach 16B alignment shared by src and cpy.
  const int h    = (4 - (m & 3)) & 3;
  const int nvec = (VDIM - h) >> 2;

  if (tid < h) {
    float v = src[tid];
    cpy[tid] = v;
    arow[tid] = f2bf(v);
    if (v > bv) { bv = v; bi = tid; }
  }
  for (int i = tid; i < nvec; i += 256) {
    const int v0i = h + (i << 2);
    f32x4 v = *(const f32x4*)(src + v0i);
    *(f32x4*)(cpy + v0i) = v;
    arow[v0i + 0] = f2bf(v[0]);
    arow[v0i + 1] = f2bf(v[1]);
    arow[v0i + 2] = f2bf(v[2]);
    arow[v0i + 3] = f2bf(v[3]);
    if (v[0] > bv) { bv = v[0]; bi = v0i; }
    if (v[1] > bv) { bv = v[1]; bi = v0i + 1; }
    if (v[2] > bv) { bv = v[2]; bi = v0i + 2; }
    if (v[3] > bv) { bv = v[3]; bi = v0i + 3; }
  }
  const int t0    = h + (nvec << 2);
  const int ntail = VDIM - t0;
  if (tid < ntail) {
    const int v0i = t0 + tid;
    float v = src[v0i];
    cpy[v0i] = v;
    arow[v0i] = f2bf(v);
    if (v > bv) { bv = v; bi = v0i; }
  }
  if (tid < KP - VDIM) arow[VDIM + tid] = 0;  // zero K-pad

  // block argmax reduction, first-index tie-break
  __shared__ float sv[256];
  __shared__ int   si[256];
  sv[tid] = bv; si[tid] = bi;
  __syncthreads();
  for (int s = 128; s > 0; s >>= 1) {
    if (tid < s) {
      float ov = sv[tid + s]; int oi = si[tid + s];
      if (ov > sv[tid] || (ov == sv[tid] && oi < si[tid])) { sv[tid] = ov; si[tid] = oi; }
    }
    __syncthreads();
  }
  if (tid == 0) out[PRED_OFF + m] = (float)si[0];
}

// ---------------------------------------------------------------------------
// Kernel 2: transpose + convert embed_weight [V][D] f32 -> BT [D][KP] bf16.
// 64x64 tiles via LDS. grid = ceil(V/64)=786 (v) * 16 (d) blocks, 256 threads.
// ---------------------------------------------------------------------------
__global__ __launch_bounds__(256) void convw_kernel(const float* __restrict__ W,
                                                    u16* __restrict__ BT)
{
  __shared__ u16 t[64][65];
  const int bx  = blockIdx.x;
  const int dt  = bx & 15;          // 16 d-tiles
  const int vt  = bx >> 4;          // 786 v-tiles
  const int v0  = vt << 6;
  const int d0  = dt << 6;
  const int tid = threadIdx.x;
  const int c16 = tid & 15;
  const int r16 = tid >> 4;

#pragma unroll
  for (int p = 0; p < 4; ++p) {
    const int v  = v0 + p * 16 + r16;
    const int vl = p * 16 + r16;
    float4 w = make_float4(0.f, 0.f, 0.f, 0.f);
    if (v < VDIM) w = *(const float4*)(W + (size_t)v * NDIM + d0 + c16 * 4);
    t[c16 * 4 + 0][vl] = f2bf(w.x);
    t[c16 * 4 + 1][vl] = f2bf(w.y);
    t[c16 * 4 + 2][vl] = f2bf(w.z);
    t[c16 * 4 + 3][vl] = f2bf(w.w);
  }
  __syncthreads();
#pragma unroll
  for (int p = 0; p < 4; ++p) {
    const int dl = p * 16 + r16;
    const int vl = c16 * 4;
    const int v  = v0 + vl;
    if (v + 3 < KP) {
      ushort4 o;
      o.x = t[dl][vl]; o.y = t[dl][vl + 1]; o.z = t[dl][vl + 2]; o.w = t[dl][vl + 3];
      *(ushort4*)(BT + (size_t)(d0 + dl) * KP + v) = o;
    }
  }
}

// ---------------------------------------------------------------------------
// Kernel 3: bf16 MFMA GEMM, 128x128 tile, BK=32, split-K=16, atomicAdd f32.
// grid = 32 mn-tiles * 16 k-chunks = 512 blocks, 256 threads (4 waves).
// ---------------------------------------------------------------------------
__global__ __launch_bounds__(256) void gemm_kernel(const u16* __restrict__ A,
                                                   const u16* __restrict__ BT,
                                                   float* __restrict__ out)
{
  __shared__ u16 ldsA[128 * 32];
  __shared__ u16 ldsB[128 * 32];

  const int bx  = blockIdx.x;
  const int kc  = bx >> 5;
  const int mn  = bx & 31;
  const int m0  = (mn & 3) << 7;
  const int n0  = (mn >> 2) << 7;
  const int ks0 = kc * SC;
  const int ks1 = min(NSTEPS, ks0 + SC);
  const int tid  = threadIdx.x;
  const int wid  = tid >> 6;
  const int lane = tid & 63;
  const int wrow = (wid >> 1) << 6;   // wave's 64x64 sub-tile
  const int wcol = (wid & 1) << 6;

  // staging: wave-linear rows, 16B per lane
  const u16* gA = A  + (size_t)(m0 + wid * 16 + (lane >> 2)) * KP + ((lane & 3) << 3);
  const u16* gB = BT + (size_t)(n0 + wid * 16 + (lane >> 2)) * KP + ((lane & 3) << 3);
  u16* lA_dst = ldsA + wid * 512;     // wave-uniform LDS base (1KB/wave)
  u16* lB_dst = ldsB + wid * 512;

  f32x4 acc[4][4] = {};

  const int r  = lane & 15;
  const int hh = lane >> 4;
  const u16* lAr = ldsA + (wrow + r) * 32 + hh * 8;
  const u16* lBr = ldsB + (wcol + r) * 32 + hh * 8;

  for (int ks = ks0; ks < ks1; ++ks) {
    const int k = ks << 5;
    __syncthreads();
    gl_lds16(gA + k,           lA_dst);
    gl_lds16(gA + k + 64 * KP, lA_dst + 2048);
    gl_lds16(gB + k,           lB_dst);
    gl_lds16(gB + k + 64 * KP, lB_dst + 2048);
    __syncthreads();

    bf16x8 av[4], bv[4];
#pragma unroll
    for (int i = 0; i < 4; ++i) av[i] = *(const bf16x8*)(lAr + i * 16 * 32);
#pragma unroll
    for (int j = 0; j < 4; ++j) bv[j] = *(const bf16x8*)(lBr + j * 16 * 32);
#pragma unroll
    for (int i = 0; i < 4; ++i)
#pragma unroll
      for (int j = 0; j < 4; ++j)
        acc[i][j] = __builtin_amdgcn_mfma_f32_16x16x32_bf16(av[i], bv[j], acc[i][j], 0, 0, 0);
  }

  // epilogue: split-K accumulate into pred_emb (zeroed by prep_kernel)
  const int col = lane & 15;
  const int r4  = (lane >> 4) << 2;
#pragma unroll
  for (int i = 0; i < 4; ++i)
#pragma unroll
    for (int j = 0; j < 4; ++j)
#pragma unroll
      for (int rr = 0; rr < 4; ++rr) {
        const int mm = m0 + wrow + i * 16 + r4 + rr;
        const int nn = n0 + wcol + j * 16 + col;
        atomicAdd(out + (size_t)mm * NDIM + nn, acc[i][j][rr]);
      }
}

// ---------------------------------------------------------------------------
extern "C" void kernel_launch(void* const* d_in, const int* in_sizes, int n_in,
                              void* d_out, int out_size, void* d_ws, size_t ws_size,
                              hipStream_t stream) {
  const float* P = (const float*)d_in[0];   // [512][50257]
  const float* W = (const float*)d_in[1];   // [50257][1024]
  float* out = (float*)d_out;
  u16* A  = (u16*)d_ws;                     // [512][KP] bf16  (51.5 MB)
  u16* BT = A + (size_t)MROWS * KP;         // [1024][KP] bf16 (103 MB)

  prep_kernel<<<MROWS, 256, 0, stream>>>(P, out, A);
  convw_kernel<<<786 * 16, 256, 0, stream>>>(W, BT);
  gemm_kernel<<<32 * KSPLIT, 256, 0, stream>>>(A, BT, out);
}